// Round 2
// baseline (1530.586 us; speedup 1.0000x reference)
//
#include <hip/hip_runtime.h>

typedef __bf16 bf16x8 __attribute__((ext_vector_type(8)));
typedef float f32x4 __attribute__((ext_vector_type(4)));

__device__ __forceinline__ unsigned short f2bf(float f) {
  union { float f; unsigned u; } v; v.f = f;
  unsigned r = v.u + 0x7fffu + ((v.u >> 16) & 1u);
  return (unsigned short)(r >> 16);
}

__device__ __forceinline__ void gload_lds16(const void* g, void* l) {
  __builtin_amdgcn_global_load_lds(
      (__attribute__((address_space(1))) void*)g,
      (__attribute__((address_space(3))) void*)l, 16, 0, 0);
}

// ---------------- cast fp32 -> bf16, x4 vectorized ----------------
__global__ void cast_kernel(const float* __restrict__ in, unsigned short* __restrict__ out, int n4) {
  int i = blockIdx.x * blockDim.x + threadIdx.x;
  if (i < n4) {
    const float4 v = reinterpret_cast<const float4*>(in)[i];
    ushort4 o;
    o.x = f2bf(v.x); o.y = f2bf(v.y); o.z = f2bf(v.z); o.w = f2bf(v.w);
    reinterpret_cast<ushort4*>(out)[i] = o;
  }
}

// ------------- transpose + cast: in [K][N] f32 -> out [N][K] bf16 -------------
__global__ void transpose_cast_kernel(const float* __restrict__ in, unsigned short* __restrict__ out,
                                      int K, int N) {
  __shared__ float t[32][33];
  int k0 = blockIdx.y * 32, n0 = blockIdx.x * 32;
  int tx = threadIdx.x, ty = threadIdx.y;
  #pragma unroll
  for (int r = ty; r < 32; r += 8) t[r][tx] = in[(size_t)(k0 + r) * N + n0 + tx];
  __syncthreads();
  #pragma unroll
  for (int r = ty; r < 32; r += 8) out[(size_t)(n0 + r) * K + k0 + tx] = f2bf(t[tx][r]);
}

// ---------------- GEMM C = A * Bt^T  (m97 structure, 128x128 tile, BK=32) ----------------
// MODE 0: QKV epilogue -> Q,K as [B,H,S,128] bf16; V TRANSPOSED as Vt [B,H,128,S] bf16
// MODE 1: fp32 output [M][N]
template<int MODE>
__global__ __launch_bounds__(256) void gemm_bt(
    const unsigned short* __restrict__ A,   // [M][K] bf16
    const unsigned short* __restrict__ Bt,  // [N][K] bf16
    float* __restrict__ outF,
    unsigned short* __restrict__ Qo,
    unsigned short* __restrict__ Ko,
    unsigned short* __restrict__ Vo,
    int M, int N, int K)
{
  __shared__ __align__(16) unsigned short As[128 * 32];
  __shared__ __align__(16) unsigned short Bs[128 * 32];
  const int tid = threadIdx.x;
  const int lane = tid & 63;
  const int w = tid >> 6;
  const int wr = (w >> 1) * 64, wc = (w & 1) * 64;
  const int lr = lane & 15, ls = lane >> 4;
  const int m0 = blockIdx.y * 128, n0 = blockIdx.x * 128;
  f32x4 acc[4][4] = {};
  for (int k0 = 0; k0 < K; k0 += 32) {
    #pragma unroll
    for (int i = 0; i < 2; ++i) {
      int idx = i * 256 + tid;            // [0,512): linear 16B chunks of the 128x32 tile
      int row = idx >> 2, colb = (idx & 3) * 8;
      gload_lds16(A + (size_t)(m0 + row) * K + k0 + colb, &As[idx * 8]);
      gload_lds16(Bt + (size_t)(n0 + row) * K + k0 + colb, &Bs[idx * 8]);
    }
    __syncthreads();
    bf16x8 af[4], bfr[4];
    #pragma unroll
    for (int t = 0; t < 4; ++t) {
      af[t]  = *reinterpret_cast<const bf16x8*>(&As[(wr + t * 16 + lr) * 32 + ls * 8]);
      bfr[t] = *reinterpret_cast<const bf16x8*>(&Bs[(wc + t * 16 + lr) * 32 + ls * 8]);
    }
    #pragma unroll
    for (int mt = 0; mt < 4; ++mt)
      #pragma unroll
      for (int nt = 0; nt < 4; ++nt)
        acc[mt][nt] = __builtin_amdgcn_mfma_f32_16x16x32_bf16(af[mt], bfr[nt], acc[mt][nt], 0, 0, 0);
    __syncthreads();
  }
  #pragma unroll
  for (int mt = 0; mt < 4; ++mt) {
    #pragma unroll
    for (int nt = 0; nt < 4; ++nt) {
      const int n = n0 + wc + nt * 16 + lr;
      #pragma unroll
      for (int r = 0; r < 4; ++r) {
        const int m = m0 + wr + mt * 16 + ls * 4 + r;
        if (MODE == 1) {
          outF[(size_t)m * N + n] = acc[mt][nt][r];
        } else {
          const int b = m >> 11, s = m & 2047;
          const int sec = n >> 11, nn = n & 2047;
          const int h = nn >> 7, d = nn & 127;
          const unsigned short val = f2bf(acc[mt][nt][r]);
          if (sec == 0)
            Qo[(((size_t)(b * 16 + h) * 2048 + s) << 7) + d] = val;
          else if (sec == 1)
            Ko[(((size_t)(b * 16 + h) * 2048 + s) << 7) + d] = val;
          else  // V transposed: Vt[b,h,d,s]
            Vo[(((size_t)(b * 16 + h)) << 18) + ((size_t)d << 11) + s] = val;
        }
      }
    }
  }
}

// ---------------- flash attention, causal, 64 q-rows/block, KVBLK=64 ----------------
// V supplied TRANSPOSED: Vt[b,h,d,s]. No barriers: p_lds is wave-private.
__global__ __launch_bounds__(256) void attn_kernel(
    const unsigned short* __restrict__ Q,
    const unsigned short* __restrict__ K,
    const unsigned short* __restrict__ Vt,
    unsigned short* __restrict__ Y)     // [B,S,C] bf16 rows for proj GEMM
{
  __shared__ __align__(16) unsigned short p_lds[4][16][72];  // 72: pad to kill bank conflicts
  const int tid = threadIdx.x;
  const int w = tid >> 6, lane = tid & 63;
  const int lr = lane & 15, ls = lane >> 4;
  const int qb = blockIdx.x, h = blockIdx.y, b = blockIdx.z;
  const size_t bh = ((size_t)(b * 16 + h)) << 18;   // * 2048 * 128
  const unsigned short* Qp = Q + bh;
  const unsigned short* Kp = K + bh;
  const unsigned short* Vp = Vt + bh;               // [128][2048]
  const int qrow0 = qb * 64 + w * 16;
  bf16x8 qf[4];
  #pragma unroll
  for (int s = 0; s < 4; ++s)
    qf[s] = *reinterpret_cast<const bf16x8*>(&Qp[(size_t)(qrow0 + lr) * 128 + s * 32 + ls * 8]);
  float mrow[4], lrow[4];
  #pragma unroll
  for (int r = 0; r < 4; ++r) { mrow[r] = -__builtin_inff(); lrow[r] = 0.f; }
  f32x4 oacc[8] = {};
  const float scale = 0.088388347648318447f;  // 1/sqrt(128)
  const int kv_end = qb * 64 + 64;
  for (int kv0 = 0; kv0 < kv_end; kv0 += 64) {
    float p[4][4];   // [kv 16-col tile][q row reg]
    #pragma unroll
    for (int t = 0; t < 4; ++t) {
      f32x4 sacc = {};
      #pragma unroll
      for (int s = 0; s < 4; ++s) {
        bf16x8 kf = *reinterpret_cast<const bf16x8*>(
            &Kp[(size_t)(kv0 + t * 16 + lr) * 128 + s * 32 + ls * 8]);
        sacc = __builtin_amdgcn_mfma_f32_16x16x32_bf16(qf[s], kf, sacc, 0, 0, 0);
      }
      const int col = kv0 + t * 16 + lr;
      #pragma unroll
      for (int r = 0; r < 4; ++r) {
        const int row = qrow0 + ls * 4 + r;
        p[t][r] = (col <= row) ? sacc[r] * scale : -__builtin_inff();
      }
    }
    // online softmax (row = ls*4+r, distributed over the 16 lanes of each ls-group)
    #pragma unroll
    for (int r = 0; r < 4; ++r) {
      float mx = fmaxf(fmaxf(p[0][r], p[1][r]), fmaxf(p[2][r], p[3][r]));
      #pragma unroll
      for (int d = 1; d < 16; d <<= 1) mx = fmaxf(mx, __shfl_xor(mx, d));
      const float mnew = fmaxf(mrow[r], mx);
      const float sc = __expf(mrow[r] - mnew);
      float rsum = 0.f;
      #pragma unroll
      for (int t = 0; t < 4; ++t) { float e = __expf(p[t][r] - mnew); p[t][r] = e; rsum += e; }
      #pragma unroll
      for (int d = 1; d < 16; d <<= 1) rsum += __shfl_xor(rsum, d);
      lrow[r] = lrow[r] * sc + rsum;
      mrow[r] = mnew;
      #pragma unroll
      for (int nt = 0; nt < 8; ++nt) oacc[nt][r] *= sc;
    }
    // stage P (bf16) to this wave's private LDS region (no barrier needed)
    #pragma unroll
    for (int t = 0; t < 4; ++t)
      #pragma unroll
      for (int r = 0; r < 4; ++r)
        p_lds[w][ls * 4 + r][t * 16 + lr] = f2bf(p[t][r]);
    // PV: O += P * V   (Vt rows are d, contiguous over kv -> 16B vector loads)
    #pragma unroll
    for (int ks = 0; ks < 2; ++ks) {
      const bf16x8 pf = *reinterpret_cast<const bf16x8*>(&p_lds[w][lr][ks * 32 + ls * 8]);
      #pragma unroll
      for (int nt = 0; nt < 8; ++nt) {
        const bf16x8 vf = *reinterpret_cast<const bf16x8*>(
            &Vp[(size_t)(nt * 16 + lr) * 2048 + kv0 + ks * 32 + ls * 8]);
        oacc[nt] = __builtin_amdgcn_mfma_f32_16x16x32_bf16(pf, vf, oacc[nt], 0, 0, 0);
      }
    }
  }
  // normalize + store Y rows (bf16) at [b, s, h*128 + d]
  const int row = qrow0 + ls * 4;
  #pragma unroll
  for (int r = 0; r < 4; ++r) {
    const float inv = 1.f / lrow[r];
    const size_t rb = ((size_t)b * 2048 + row + r) * 2048 + h * 128 + lr;
    #pragma unroll
    for (int nt = 0; nt < 8; ++nt)
      Y[rb + nt * 16] = f2bf(oacc[nt][r] * inv);
  }
}

extern "C" void kernel_launch(void* const* d_in, const int* in_sizes, int n_in,
                              void* d_out, int out_size, void* d_ws, size_t ws_size,
                              hipStream_t stream) {
  const float* x  = (const float*)d_in[0];   // [4,2048,2048]
  const float* Wa = (const float*)d_in[1];   // [2048,6144]
  const float* Wp = (const float*)d_in[2];   // [2048,2048]
  float* out = (float*)d_out;                // [4,2048,2048] f32

  unsigned short* ws  = (unsigned short*)d_ws;
  unsigned short* xb  = ws;                          // 8192*2048 bf16
  unsigned short* wat = xb  + (size_t)8192 * 2048;   // 6144*2048 bf16 (W_attn^T)
  unsigned short* wpt = wat + (size_t)6144 * 2048;   // 2048*2048 bf16 (W_proj^T)
  unsigned short* Qb  = wpt + (size_t)2048 * 2048;   // [4,16,2048,128] bf16
  unsigned short* Kb  = Qb  + (size_t)4 * 16 * 2048 * 128;
  unsigned short* Vtb = Kb  + (size_t)4 * 16 * 2048 * 128;  // [4,16,128,2048] bf16 (V^T)
  unsigned short* yb  = Vtb + (size_t)4 * 16 * 2048 * 128;  // [4,2048,2048] bf16

  cast_kernel<<<dim3(16384), dim3(256), 0, stream>>>(x, xb, (8192 * 2048) / 4);
  transpose_cast_kernel<<<dim3(192, 64), dim3(32, 8), 0, stream>>>(Wa, wat, 2048, 6144);
  transpose_cast_kernel<<<dim3(64, 64), dim3(32, 8), 0, stream>>>(Wp, wpt, 2048, 2048);

  gemm_bt<0><<<dim3(48, 64), dim3(256), 0, stream>>>(xb, wat, nullptr, Qb, Kb, Vtb,
                                                     8192, 6144, 2048);
  attn_kernel<<<dim3(32, 16, 4), dim3(256), 0, stream>>>(Qb, Kb, Vtb, yb);
  gemm_bt<1><<<dim3(16, 64), dim3(256), 0, stream>>>(yb, wpt, out, nullptr, nullptr, nullptr,
                                                     8192, 2048, 2048);
}

// Round 4
// 913.831 us; speedup vs baseline: 1.6749x; 1.6749x over previous
//
#include <hip/hip_runtime.h>

typedef __bf16 bf16x8 __attribute__((ext_vector_type(8)));
typedef float f32x4 __attribute__((ext_vector_type(4)));

__device__ __forceinline__ unsigned short f2bf(float f) {
  union { float f; unsigned u; } v; v.f = f;
  unsigned r = v.u + 0x7fffu + ((v.u >> 16) & 1u);
  return (unsigned short)(r >> 16);
}

__device__ __forceinline__ void gload_lds16(const void* g, void* l) {
  __builtin_amdgcn_global_load_lds(
      (__attribute__((address_space(1))) void*)g,
      (__attribute__((address_space(3))) void*)l, 16, 0, 0);
}

// ---------------- cast fp32 -> bf16, x4 vectorized ----------------
__global__ void cast_kernel(const float* __restrict__ in, unsigned short* __restrict__ out, int n4) {
  int i = blockIdx.x * blockDim.x + threadIdx.x;
  if (i < n4) {
    const float4 v = reinterpret_cast<const float4*>(in)[i];
    ushort4 o;
    o.x = f2bf(v.x); o.y = f2bf(v.y); o.z = f2bf(v.z); o.w = f2bf(v.w);
    reinterpret_cast<ushort4*>(out)[i] = o;
  }
}

// ------------- transpose + cast: in [K][N] f32 -> out [N][K] bf16 -------------
__global__ void transpose_cast_kernel(const float* __restrict__ in, unsigned short* __restrict__ out,
                                      int K, int N) {
  __shared__ float t[32][33];
  int k0 = blockIdx.y * 32, n0 = blockIdx.x * 32;
  int tx = threadIdx.x, ty = threadIdx.y;
  #pragma unroll
  for (int r = ty; r < 32; r += 8) t[r][tx] = in[(size_t)(k0 + r) * N + n0 + tx];
  __syncthreads();
  #pragma unroll
  for (int r = ty; r < 32; r += 8) out[(size_t)(n0 + r) * K + k0 + tx] = f2bf(t[tx][r]);
}

// ---------------- GEMM C = A * Bt^T  (m97 structure, 128x128 tile, BK=32) ----------------
// MODE 0: QKV epilogue -> Q,K as [B,H,S,128] bf16; V TRANSPOSED as Vt [B,H,128,S] bf16
// MODE 1: fp32 output [M][N]
template<int MODE>
__global__ __launch_bounds__(256) void gemm_bt(
    const unsigned short* __restrict__ A,   // [M][K] bf16
    const unsigned short* __restrict__ Bt,  // [N][K] bf16
    float* __restrict__ outF,
    unsigned short* __restrict__ Qo,
    unsigned short* __restrict__ Ko,
    unsigned short* __restrict__ Vo,
    int M, int N, int K)
{
  __shared__ __align__(16) unsigned short As[128 * 32];
  __shared__ __align__(16) unsigned short Bs[128 * 32];
  const int tid = threadIdx.x;
  const int lane = tid & 63;
  const int w = tid >> 6;
  const int wr = (w >> 1) * 64, wc = (w & 1) * 64;
  const int lr = lane & 15, ls = lane >> 4;
  const int m0 = blockIdx.y * 128, n0 = blockIdx.x * 128;
  f32x4 acc[4][4] = {};
  for (int k0 = 0; k0 < K; k0 += 32) {
    #pragma unroll
    for (int i = 0; i < 2; ++i) {
      int idx = i * 256 + tid;            // [0,512): linear 16B chunks of the 128x32 tile
      int row = idx >> 2, colb = (idx & 3) * 8;
      gload_lds16(A + (size_t)(m0 + row) * K + k0 + colb, &As[idx * 8]);
      gload_lds16(Bt + (size_t)(n0 + row) * K + k0 + colb, &Bs[idx * 8]);
    }
    __syncthreads();
    bf16x8 af[4], bfr[4];
    #pragma unroll
    for (int t = 0; t < 4; ++t) {
      af[t]  = *reinterpret_cast<const bf16x8*>(&As[(wr + t * 16 + lr) * 32 + ls * 8]);
      bfr[t] = *reinterpret_cast<const bf16x8*>(&Bs[(wc + t * 16 + lr) * 32 + ls * 8]);
    }
    #pragma unroll
    for (int mt = 0; mt < 4; ++mt)
      #pragma unroll
      for (int nt = 0; nt < 4; ++nt)
        acc[mt][nt] = __builtin_amdgcn_mfma_f32_16x16x32_bf16(af[mt], bfr[nt], acc[mt][nt], 0, 0, 0);
    __syncthreads();
  }
  #pragma unroll
  for (int mt = 0; mt < 4; ++mt) {
    #pragma unroll
    for (int nt = 0; nt < 4; ++nt) {
      const int n = n0 + wc + nt * 16 + lr;
      #pragma unroll
      for (int r = 0; r < 4; ++r) {
        const int m = m0 + wr + mt * 16 + ls * 4 + r;
        if (MODE == 1) {
          outF[(size_t)m * N + n] = acc[mt][nt][r];
        } else {
          const int b = m >> 11, s = m & 2047;
          const int sec = n >> 11, nn = n & 2047;
          const int h = nn >> 7, d = nn & 127;
          const unsigned short val = f2bf(acc[mt][nt][r]);
          if (sec == 0)
            Qo[(((size_t)(b * 16 + h) * 2048 + s) << 7) + d] = val;
          else if (sec == 1)
            Ko[(((size_t)(b * 16 + h) * 2048 + s) << 7) + d] = val;
          else  // V transposed: Vt[b,h,d,s]
            Vo[(((size_t)(b * 16 + h)) << 18) + ((size_t)d << 11) + s] = val;
        }
      }
    }
  }
}

// ---------------- flash attention, causal, 64 q-rows/block, KVBLK=64 ----------------
// K and Vt staged in LDS (XOR-swizzled both sides), reg-staged issue-early/write-late.
__global__ __launch_bounds__(256) void attn_kernel(
    const unsigned short* __restrict__ Q,
    const unsigned short* __restrict__ K,
    const unsigned short* __restrict__ Vt,   // [B,H,128,2048]
    unsigned short* __restrict__ Y)          // [B,S,C] bf16 rows for proj GEMM
{
  __shared__ __align__(16) unsigned short Ks[64 * 128];   // [kv 64][d 128], chunk-swizzled
  __shared__ __align__(16) unsigned short Vs[128 * 64];   // [d 128][kv 64], chunk-swizzled
  __shared__ __align__(16) unsigned short p_lds[4][16][80];  // 160B rows: 16B-aligned
  const int tid = threadIdx.x;
  const int w = tid >> 6, lane = tid & 63;
  const int lr = lane & 15, ls = lane >> 4;
  const int qb = 31 - blockIdx.x;    // long blocks first (tail balance)
  const int h = blockIdx.y, b = blockIdx.z;
  const size_t bh = ((size_t)(b * 16 + h)) << 18;   // * 2048 * 128
  const unsigned short* Qp = Q + bh;
  const unsigned short* Kp = K + bh;
  const unsigned short* Vp = Vt + bh;               // [128][2048]
  const int qrow0 = qb * 64 + w * 16;
  bf16x8 qf[4];
  #pragma unroll
  for (int s = 0; s < 4; ++s)
    qf[s] = *reinterpret_cast<const bf16x8*>(&Qp[(size_t)(qrow0 + lr) * 128 + s * 32 + ls * 8]);
  float mrow[4], lrow[4];
  #pragma unroll
  for (int r = 0; r < 4; ++r) { mrow[r] = -__builtin_inff(); lrow[r] = 0.f; }
  f32x4 oacc[8] = {};
  const float scale = 0.088388347648318447f;  // 1/sqrt(128)
  const int kv_end = qb * 64 + 64;

  // staging registers (4 K chunks + 4 V chunks per thread, 16B each)
  bf16x8 kpre[4], vpre[4];
  // per-thread stage coordinates
  const int krow0 = tid >> 4, kc = tid & 15;          // K: rows krow0 + i*16, chunk kc
  const int vrow0 = tid >> 3, vc = tid & 7;           // V: rows vrow0 + i*32, chunk vc
  #pragma unroll
  for (int i = 0; i < 4; ++i) {
    kpre[i] = *reinterpret_cast<const bf16x8*>(&Kp[(size_t)(krow0 + i * 16) * 128 + kc * 8]);
    vpre[i] = *reinterpret_cast<const bf16x8*>(&Vp[(size_t)(vrow0 + i * 32) * 2048 + vc * 8]);
  }

  // swizzled LDS read chunk offsets (ushort index): constant per thread
  int kcol[4];
  #pragma unroll
  for (int s = 0; s < 4; ++s) kcol[s] = ((4 * s + ls) ^ (lr & 7)) * 8;

  for (int kv0 = 0; kv0 < kv_end; kv0 += 64) {
    __syncthreads();   // all waves done reading previous tile
    #pragma unroll
    for (int i = 0; i < 4; ++i) {
      const int krow = krow0 + i * 16;
      *reinterpret_cast<bf16x8*>(&Ks[krow * 128 + ((kc ^ (krow & 7)) * 8)]) = kpre[i];
      const int vrow = vrow0 + i * 32;
      *reinterpret_cast<bf16x8*>(&Vs[vrow * 64 + ((vc ^ (vrow & 7)) * 8)]) = vpre[i];
    }
    if (kv0 + 64 < kv_end) {   // issue next tile's loads early (hide under compute)
      const int kvn = kv0 + 64;
      #pragma unroll
      for (int i = 0; i < 4; ++i) {
        kpre[i] = *reinterpret_cast<const bf16x8*>(&Kp[(size_t)(kvn + krow0 + i * 16) * 128 + kc * 8]);
        vpre[i] = *reinterpret_cast<const bf16x8*>(&Vp[(size_t)(vrow0 + i * 32) * 2048 + kvn + vc * 8]);
      }
    }
    __syncthreads();   // tile visible

    float p[4][4];   // [kv 16-col tile][q row reg]
    #pragma unroll
    for (int t = 0; t < 4; ++t) {
      f32x4 sacc = {};
      #pragma unroll
      for (int s = 0; s < 4; ++s) {
        const bf16x8 kf = *reinterpret_cast<const bf16x8*>(&Ks[(t * 16 + lr) * 128 + kcol[s]]);
        sacc = __builtin_amdgcn_mfma_f32_16x16x32_bf16(qf[s], kf, sacc, 0, 0, 0);
      }
      const int col = kv0 + t * 16 + lr;
      #pragma unroll
      for (int r = 0; r < 4; ++r) {
        const int row = qrow0 + ls * 4 + r;
        p[t][r] = (col <= row) ? sacc[r] * scale : -__builtin_inff();
      }
    }
    // online softmax; row r lives across the 16 lanes of each ls-group
    float mx[4];
    int defer = 1;
    #pragma unroll
    for (int r = 0; r < 4; ++r) {
      float m = fmaxf(fmaxf(p[0][r], p[1][r]), fmaxf(p[2][r], p[3][r]));
      #pragma unroll
      for (int d = 1; d < 16; d <<= 1) m = fmaxf(m, __shfl_xor(m, d));
      mx[r] = m;
      defer &= (m <= mrow[r] + 8.f);
    }
    if (__all(defer)) {
      // keep old max: P bounded by e^8, f32 accum tolerates
      #pragma unroll
      for (int r = 0; r < 4; ++r) {
        float rsum = 0.f;
        #pragma unroll
        for (int t = 0; t < 4; ++t) { float e = __expf(p[t][r] - mrow[r]); p[t][r] = e; rsum += e; }
        #pragma unroll
        for (int d = 1; d < 16; d <<= 1) rsum += __shfl_xor(rsum, d);
        lrow[r] += rsum;
      }
    } else {
      #pragma unroll
      for (int r = 0; r < 4; ++r) {
        const float mnew = fmaxf(mrow[r], mx[r]);
        const float sc = __expf(mrow[r] - mnew);
        float rsum = 0.f;
        #pragma unroll
        for (int t = 0; t < 4; ++t) { float e = __expf(p[t][r] - mnew); p[t][r] = e; rsum += e; }
        #pragma unroll
        for (int d = 1; d < 16; d <<= 1) rsum += __shfl_xor(rsum, d);
        lrow[r] = lrow[r] * sc + rsum;
        mrow[r] = mnew;
        #pragma unroll
        for (int nt = 0; nt < 8; ++nt) oacc[nt][r] *= sc;
      }
    }
    // stage P (bf16) to this wave's private LDS region (no barrier needed)
    #pragma unroll
    for (int t = 0; t < 4; ++t)
      #pragma unroll
      for (int r = 0; r < 4; ++r)
        p_lds[w][ls * 4 + r][t * 16 + lr] = f2bf(p[t][r]);
    // PV: O += P * V  (both operands from LDS; V chunk 4*ks+ls, XOR lr&7)
    #pragma unroll
    for (int ks = 0; ks < 2; ++ks) {
      const bf16x8 pf = *reinterpret_cast<const bf16x8*>(&p_lds[w][lr][ks * 32 + ls * 8]);
      #pragma unroll
      for (int nt = 0; nt < 8; ++nt) {
        const bf16x8 vf = *reinterpret_cast<const bf16x8*>(&Vs[(nt * 16 + lr) * 64 + kcol[ks]]);
        oacc[nt] = __builtin_amdgcn_mfma_f32_16x16x32_bf16(pf, vf, oacc[nt], 0, 0, 0);
      }
    }
  }
  // normalize + store Y rows (bf16) at [b, s, h*128 + d]
  const int row = qrow0 + ls * 4;
  #pragma unroll
  for (int r = 0; r < 4; ++r) {
    const float inv = 1.f / lrow[r];
    const size_t rb = ((size_t)b * 2048 + row + r) * 2048 + h * 128 + lr;
    #pragma unroll
    for (int nt = 0; nt < 8; ++nt)
      Y[rb + nt * 16] = f2bf(oacc[nt][r] * inv);
  }
}

extern "C" void kernel_launch(void* const* d_in, const int* in_sizes, int n_in,
                              void* d_out, int out_size, void* d_ws, size_t ws_size,
                              hipStream_t stream) {
  const float* x  = (const float*)d_in[0];   // [4,2048,2048]
  const float* Wa = (const float*)d_in[1];   // [2048,6144]
  const float* Wp = (const float*)d_in[2];   // [2048,2048]
  float* out = (float*)d_out;                // [4,2048,2048] f32

  unsigned short* ws  = (unsigned short*)d_ws;
  unsigned short* xb  = ws;                          // 8192*2048 bf16
  unsigned short* wat = xb  + (size_t)8192 * 2048;   // 6144*2048 bf16 (W_attn^T)
  unsigned short* wpt = wat + (size_t)6144 * 2048;   // 2048*2048 bf16 (W_proj^T)
  unsigned short* Qb  = wpt + (size_t)2048 * 2048;   // [4,16,2048,128] bf16
  unsigned short* Kb  = Qb  + (size_t)4 * 16 * 2048 * 128;
  unsigned short* Vtb = Kb  + (size_t)4 * 16 * 2048 * 128;  // [4,16,128,2048] bf16 (V^T)
  unsigned short* yb  = Vtb + (size_t)4 * 16 * 2048 * 128;  // [4,2048,2048] bf16

  cast_kernel<<<dim3(16384), dim3(256), 0, stream>>>(x, xb, (8192 * 2048) / 4);
  transpose_cast_kernel<<<dim3(192, 64), dim3(32, 8), 0, stream>>>(Wa, wat, 2048, 6144);
  transpose_cast_kernel<<<dim3(64, 64), dim3(32, 8), 0, stream>>>(Wp, wpt, 2048, 2048);

  gemm_bt<0><<<dim3(48, 64), dim3(256), 0, stream>>>(xb, wat, nullptr, Qb, Kb, Vtb,
                                                     8192, 6144, 2048);
  attn_kernel<<<dim3(32, 16, 4), dim3(256), 0, stream>>>(Qb, Kb, Vtb, yb);
  gemm_bt<1><<<dim3(16, 64), dim3(256), 0, stream>>>(yb, wpt, out, nullptr, nullptr, nullptr,
                                                     8192, 2048, 2048);
}

// Round 6
// 801.842 us; speedup vs baseline: 1.9088x; 1.1397x over previous
//
#include <hip/hip_runtime.h>

typedef __bf16 bf16x8 __attribute__((ext_vector_type(8)));
typedef float f32x4 __attribute__((ext_vector_type(4)));

__device__ __forceinline__ unsigned short f2bf(float f) {
  union { float f; unsigned u; } v; v.f = f;
  unsigned r = v.u + 0x7fffu + ((v.u >> 16) & 1u);
  return (unsigned short)(r >> 16);
}

__device__ __forceinline__ void gload_lds16(const void* g, void* l) {
  __builtin_amdgcn_global_load_lds(
      (__attribute__((address_space(1))) void*)g,
      (__attribute__((address_space(3))) void*)l, 16, 0, 0);
}

// ---------------- cast fp32 -> bf16, x4 vectorized ----------------
__global__ void cast_kernel(const float* __restrict__ in, unsigned short* __restrict__ out, int n4) {
  int i = blockIdx.x * blockDim.x + threadIdx.x;
  if (i < n4) {
    const float4 v = reinterpret_cast<const float4*>(in)[i];
    ushort4 o;
    o.x = f2bf(v.x); o.y = f2bf(v.y); o.z = f2bf(v.z); o.w = f2bf(v.w);
    reinterpret_cast<ushort4*>(out)[i] = o;
  }
}

// ------------- transpose + cast: in [K][N] f32 -> out [N][K] bf16 -------------
__global__ void transpose_cast_kernel(const float* __restrict__ in, unsigned short* __restrict__ out,
                                      int K, int N) {
  __shared__ float t[32][33];
  int k0 = blockIdx.y * 32, n0 = blockIdx.x * 32;
  int tx = threadIdx.x, ty = threadIdx.y;
  #pragma unroll
  for (int r = ty; r < 32; r += 8) t[r][tx] = in[(size_t)(k0 + r) * N + n0 + tx];
  __syncthreads();
  #pragma unroll
  for (int r = ty; r < 32; r += 8) out[(size_t)(n0 + r) * K + k0 + tx] = f2bf(t[tx][r]);
}

// ---------------- GEMM C = A * Bt^T  (m97 structure, 128x128 tile, BK=32) ----------------
// 1D grid with chunked XCD swizzle (nwg % 8 == 0). nx = N/128 tiles.
// MODE 0: QKV epilogue -> Q,K as [B,H,S,128] bf16; V TRANSPOSED as Vt [B,H,128,S] bf16
// MODE 1: fp32 output [M][N]
template<int MODE>
__global__ __launch_bounds__(256) void gemm_bt(
    const unsigned short* __restrict__ A,   // [M][K] bf16
    const unsigned short* __restrict__ Bt,  // [N][K] bf16
    float* __restrict__ outF,
    unsigned short* __restrict__ Qo,
    unsigned short* __restrict__ Ko,
    unsigned short* __restrict__ Vo,
    int M, int N, int K, int nx)
{
  __shared__ __align__(16) unsigned short As[128 * 32];
  __shared__ __align__(16) unsigned short Bs[128 * 32];
  const int tid = threadIdx.x;
  const int lane = tid & 63;
  const int w = tid >> 6;
  const int wr = (w >> 1) * 64, wc = (w & 1) * 64;
  const int lr = lane & 15, ls = lane >> 4;
  // chunked XCD swizzle: consecutive wgids on one XCD share the A row-panel
  const int nwg = gridDim.x;
  const int wgid = (blockIdx.x & 7) * (nwg >> 3) + (blockIdx.x >> 3);
  const int m0 = (wgid / nx) * 128, n0 = (wgid % nx) * 128;
  f32x4 acc[4][4] = {};
  for (int k0 = 0; k0 < K; k0 += 32) {
    #pragma unroll
    for (int i = 0; i < 2; ++i) {
      int idx = i * 256 + tid;            // [0,512): linear 16B chunks of the 128x32 tile
      int row = idx >> 2, colb = (idx & 3) * 8;
      gload_lds16(A + (size_t)(m0 + row) * K + k0 + colb, &As[idx * 8]);
      gload_lds16(Bt + (size_t)(n0 + row) * K + k0 + colb, &Bs[idx * 8]);
    }
    __syncthreads();
    bf16x8 af[4], bfr[4];
    #pragma unroll
    for (int t = 0; t < 4; ++t) {
      af[t]  = *reinterpret_cast<const bf16x8*>(&As[(wr + t * 16 + lr) * 32 + ls * 8]);
      bfr[t] = *reinterpret_cast<const bf16x8*>(&Bs[(wc + t * 16 + lr) * 32 + ls * 8]);
    }
    #pragma unroll
    for (int mt = 0; mt < 4; ++mt)
      #pragma unroll
      for (int nt = 0; nt < 4; ++nt)
        acc[mt][nt] = __builtin_amdgcn_mfma_f32_16x16x32_bf16(af[mt], bfr[nt], acc[mt][nt], 0, 0, 0);
    __syncthreads();
  }
  #pragma unroll
  for (int mt = 0; mt < 4; ++mt) {
    #pragma unroll
    for (int nt = 0; nt < 4; ++nt) {
      const int n = n0 + wc + nt * 16 + lr;
      #pragma unroll
      for (int r = 0; r < 4; ++r) {
        const int m = m0 + wr + mt * 16 + ls * 4 + r;
        if (MODE == 1) {
          outF[(size_t)m * N + n] = acc[mt][nt][r];
        } else {
          const int b = m >> 11, s = m & 2047;
          const int sec = n >> 11, nn = n & 2047;
          const int h = nn >> 7, d = nn & 127;
          const unsigned short val = f2bf(acc[mt][nt][r]);
          if (sec == 0)
            Qo[(((size_t)(b * 16 + h) * 2048 + s) << 7) + d] = val;
          else if (sec == 1)
            Ko[(((size_t)(b * 16 + h) * 2048 + s) << 7) + d] = val;
          else  // V transposed: Vt[b,h,d,s]
            Vo[(((size_t)(b * 16 + h)) << 18) + ((size_t)d << 11) + s] = val;
        }
      }
    }
  }
}

// ---------------- flash attention, causal, 64 q-rows/block, KVBLK=64 ----------------
// K and Vt staged in LDS (XOR-swizzled both sides), reg-staged issue-early/write-late.
// 1D grid (2048) with XCD-locality mapping: all 32 qb-blocks of one (b,h) run
// consecutively on ONE XCD so its 1MB K/V stays L2-resident.
__global__ __launch_bounds__(256) void attn_kernel(
    const unsigned short* __restrict__ Q,
    const unsigned short* __restrict__ K,
    const unsigned short* __restrict__ Vt,   // [B,H,128,2048]
    unsigned short* __restrict__ Y)          // [B,S,C] bf16 rows for proj GEMM
{
  __shared__ __align__(16) unsigned short Ks[64 * 128];   // [kv 64][d 128], chunk-swizzled
  __shared__ __align__(16) unsigned short Vs[128 * 64];   // [d 128][kv 64], chunk-swizzled
  __shared__ __align__(16) unsigned short p_lds[4][16][80];  // 160B rows: 16B-aligned
  const int tid = threadIdx.x;
  const int w = tid >> 6, lane = tid & 63;
  const int lr = lane & 15, ls = lane >> 4;
  // XCD-locality decomposition of blockIdx.x (grid = 2048 = 8 xcd * 8 bh-group * 32 qb)
  const int flat = blockIdx.x;
  const int xcd = flat & 7;
  const int idx = flat >> 3;            // 0..255 sequential on this XCD
  const int bh = (idx >> 5) * 8 + xcd;  // 0..63: all 32 qb of this bh contiguous on xcd
  const int qb = 31 - (idx & 31);       // long blocks first
  const int h = bh & 15, b = bh >> 4;
  const size_t bhoff = ((size_t)bh) << 18;   // * 2048 * 128
  const unsigned short* Qp = Q + bhoff;
  const unsigned short* Kp = K + bhoff;
  const unsigned short* Vp = Vt + bhoff;     // [128][2048]
  const int qrow0 = qb * 64 + w * 16;
  bf16x8 qf[4];
  #pragma unroll
  for (int s = 0; s < 4; ++s)
    qf[s] = *reinterpret_cast<const bf16x8*>(&Qp[(size_t)(qrow0 + lr) * 128 + s * 32 + ls * 8]);
  float mrow[4], lrow[4];
  #pragma unroll
  for (int r = 0; r < 4; ++r) { mrow[r] = -__builtin_inff(); lrow[r] = 0.f; }
  f32x4 oacc[8] = {};
  const float scale = 0.088388347648318447f;  // 1/sqrt(128)
  const int kv_end = qb * 64 + 64;

  // staging registers (4 K chunks + 4 V chunks per thread, 16B each)
  bf16x8 kpre[4], vpre[4];
  const int krow0 = tid >> 4, kc = tid & 15;          // K: rows krow0 + i*16, chunk kc
  const int vrow0 = tid >> 3, vc = tid & 7;           // V: rows vrow0 + i*32, chunk vc
  #pragma unroll
  for (int i = 0; i < 4; ++i) {
    kpre[i] = *reinterpret_cast<const bf16x8*>(&Kp[(size_t)(krow0 + i * 16) * 128 + kc * 8]);
    vpre[i] = *reinterpret_cast<const bf16x8*>(&Vp[(size_t)(vrow0 + i * 32) * 2048 + vc * 8]);
  }

  // swizzled LDS read chunk offsets (ushort index): constant per thread
  int kcol[4];
  #pragma unroll
  for (int s = 0; s < 4; ++s) kcol[s] = ((4 * s + ls) ^ (lr & 7)) * 8;

  for (int kv0 = 0; kv0 < kv_end; kv0 += 64) {
    __syncthreads();   // all waves done reading previous tile
    #pragma unroll
    for (int i = 0; i < 4; ++i) {
      const int krow = krow0 + i * 16;
      *reinterpret_cast<bf16x8*>(&Ks[krow * 128 + ((kc ^ (krow & 7)) * 8)]) = kpre[i];
      const int vrow = vrow0 + i * 32;
      *reinterpret_cast<bf16x8*>(&Vs[vrow * 64 + ((vc ^ (vrow & 7)) * 8)]) = vpre[i];
    }
    if (kv0 + 64 < kv_end) {   // issue next tile's loads early (hide under compute)
      const int kvn = kv0 + 64;
      #pragma unroll
      for (int i = 0; i < 4; ++i) {
        kpre[i] = *reinterpret_cast<const bf16x8*>(&Kp[(size_t)(kvn + krow0 + i * 16) * 128 + kc * 8]);
        vpre[i] = *reinterpret_cast<const bf16x8*>(&Vp[(size_t)(vrow0 + i * 32) * 2048 + kvn + vc * 8]);
      }
    }
    __syncthreads();   // tile visible

    float p[4][4];   // [kv 16-col tile][q row reg]
    #pragma unroll
    for (int t = 0; t < 4; ++t) {
      f32x4 sacc = {};
      #pragma unroll
      for (int s = 0; s < 4; ++s) {
        const bf16x8 kf = *reinterpret_cast<const bf16x8*>(&Ks[(t * 16 + lr) * 128 + kcol[s]]);
        sacc = __builtin_amdgcn_mfma_f32_16x16x32_bf16(qf[s], kf, sacc, 0, 0, 0);
      }
      const int col = kv0 + t * 16 + lr;
      #pragma unroll
      for (int r = 0; r < 4; ++r) {
        const int row = qrow0 + ls * 4 + r;
        p[t][r] = (col <= row) ? sacc[r] * scale : -__builtin_inff();
      }
    }
    // online softmax; row r lives across the 16 lanes of each ls-group
    float mx[4];
    int defer = 1;
    #pragma unroll
    for (int r = 0; r < 4; ++r) {
      float m = fmaxf(fmaxf(p[0][r], p[1][r]), fmaxf(p[2][r], p[3][r]));
      #pragma unroll
      for (int d = 1; d < 16; d <<= 1) m = fmaxf(m, __shfl_xor(m, d));
      mx[r] = m;
      defer &= (m <= mrow[r] + 8.f);
    }
    if (__all(defer)) {
      // keep old max: P bounded by e^8, f32 accum tolerates
      #pragma unroll
      for (int r = 0; r < 4; ++r) {
        float rsum = 0.f;
        #pragma unroll
        for (int t = 0; t < 4; ++t) { float e = __expf(p[t][r] - mrow[r]); p[t][r] = e; rsum += e; }
        #pragma unroll
        for (int d = 1; d < 16; d <<= 1) rsum += __shfl_xor(rsum, d);
        lrow[r] += rsum;
      }
    } else {
      #pragma unroll
      for (int r = 0; r < 4; ++r) {
        const float mnew = fmaxf(mrow[r], mx[r]);
        const float sc = __expf(mrow[r] - mnew);
        float rsum = 0.f;
        #pragma unroll
        for (int t = 0; t < 4; ++t) { float e = __expf(p[t][r] - mnew); p[t][r] = e; rsum += e; }
        #pragma unroll
        for (int d = 1; d < 16; d <<= 1) rsum += __shfl_xor(rsum, d);
        lrow[r] = lrow[r] * sc + rsum;
        mrow[r] = mnew;
        #pragma unroll
        for (int nt = 0; nt < 8; ++nt) oacc[nt][r] *= sc;
      }
    }
    // stage P (bf16) to this wave's private LDS region (no barrier needed)
    #pragma unroll
    for (int t = 0; t < 4; ++t)
      #pragma unroll
      for (int r = 0; r < 4; ++r)
        p_lds[w][ls * 4 + r][t * 16 + lr] = f2bf(p[t][r]);
    // PV: O += P * V  (both operands from LDS; V chunk 4*ks+ls, XOR lr&7)
    #pragma unroll
    for (int ks = 0; ks < 2; ++ks) {
      const bf16x8 pf = *reinterpret_cast<const bf16x8*>(&p_lds[w][lr][ks * 32 + ls * 8]);
      #pragma unroll
      for (int nt = 0; nt < 8; ++nt) {
        const bf16x8 vf = *reinterpret_cast<const bf16x8*>(&Vs[(nt * 16 + lr) * 64 + kcol[ks]]);
        oacc[nt] = __builtin_amdgcn_mfma_f32_16x16x32_bf16(pf, vf, oacc[nt], 0, 0, 0);
      }
    }
  }
  // normalize + store Y rows (bf16) at [b, s, h*128 + d]
  const int row = qrow0 + ls * 4;
  #pragma unroll
  for (int r = 0; r < 4; ++r) {
    const float inv = 1.f / lrow[r];
    const size_t rb = ((size_t)b * 2048 + row + r) * 2048 + h * 128 + lr;
    #pragma unroll
    for (int nt = 0; nt < 8; ++nt)
      Y[rb + nt * 16] = f2bf(oacc[nt][r] * inv);
  }
}

extern "C" void kernel_launch(void* const* d_in, const int* in_sizes, int n_in,
                              void* d_out, int out_size, void* d_ws, size_t ws_size,
                              hipStream_t stream) {
  const float* x  = (const float*)d_in[0];   // [4,2048,2048]
  const float* Wa = (const float*)d_in[1];   // [2048,6144]
  const float* Wp = (const float*)d_in[2];   // [2048,2048]
  float* out = (float*)d_out;                // [4,2048,2048] f32

  unsigned short* ws  = (unsigned short*)d_ws;
  unsigned short* xb  = ws;                          // 8192*2048 bf16
  unsigned short* wat = xb  + (size_t)8192 * 2048;   // 6144*2048 bf16 (W_attn^T)
  unsigned short* wpt = wat + (size_t)6144 * 2048;   // 2048*2048 bf16 (W_proj^T)
  unsigned short* Qb  = wpt + (size_t)2048 * 2048;   // [4,16,2048,128] bf16
  unsigned short* Kb  = Qb  + (size_t)4 * 16 * 2048 * 128;
  unsigned short* Vtb = Kb  + (size_t)4 * 16 * 2048 * 128;  // [4,16,128,2048] bf16 (V^T)
  unsigned short* yb  = Vtb + (size_t)4 * 16 * 2048 * 128;  // [4,2048,2048] bf16

  cast_kernel<<<dim3(16384), dim3(256), 0, stream>>>(x, xb, (8192 * 2048) / 4);
  transpose_cast_kernel<<<dim3(192, 64), dim3(32, 8), 0, stream>>>(Wa, wat, 2048, 6144);
  transpose_cast_kernel<<<dim3(64, 64), dim3(32, 8), 0, stream>>>(Wp, wpt, 2048, 2048);

  gemm_bt<0><<<dim3(3072), dim3(256), 0, stream>>>(xb, wat, nullptr, Qb, Kb, Vtb,
                                                   8192, 6144, 2048, 48);
  attn_kernel<<<dim3(2048), dim3(256), 0, stream>>>(Qb, Kb, Vtb, yb);
  gemm_bt<1><<<dim3(1024), dim3(256), 0, stream>>>(yb, wpt, out, nullptr, nullptr, nullptr,
                                                   8192, 2048, 2048, 16);
}